// Round 1
// baseline (660.889 us; speedup 1.0000x reference)
//
#include <hip/hip_runtime.h>
#include <hip/hip_bf16.h>

#define HIDDEN 1152
#define IN_DIM 768
#define POS_SIZE 64
#define M_TOTAL (16 * 4096)

#define BM 128
#define BN 128
#define BK 32
#define NTILES (HIDDEN / BN) /* 9 */

typedef _Float16 f16x8 __attribute__((ext_vector_type(8)));
typedef float f32x4 __attribute__((ext_vector_type(4)));
typedef float f32x8v __attribute__((ext_vector_type(8)));

typedef __attribute__((address_space(1))) const void global_cv;
typedef __attribute__((address_space(3))) void lds_v;

__device__ __forceinline__ void async16(const void* g, void* l) {
    __builtin_amdgcn_global_load_lds((global_cv*)g, (lds_v*)l, 16, 0, 0);
}

// ---------------- fp32 -> f16 conversion ----------------
__global__ __launch_bounds__(256) void cvt_f32_f16(const float* __restrict__ in,
                                                   _Float16* __restrict__ out, int n8) {
    int i = blockIdx.x * 256 + threadIdx.x;
    int stride = gridDim.x * 256;
    for (; i < n8; i += stride) {
        f32x8v x = ((const f32x8v*)in)[i];
        f16x8 h = __builtin_convertvector(x, f16x8);
        ((f16x8*)out)[i] = h;
    }
}

// ---------------- MFMA GEMM + PE epilogue ----------------
// A: [M, 768] f16 row-major; Wh: [1152, 768] f16 row-major (== B^T, N x K)
// C[m][n] = sum_k A[m][k] * Wh[n][k]  (+ PE gather, masked)
__global__ __launch_bounds__(256) void gemm_pe(const _Float16* __restrict__ A,
                                               const _Float16* __restrict__ Wh,
                                               const int* __restrict__ pos,   // [M,2]
                                               const int* __restrict__ pad,   // [M]
                                               const float* __restrict__ table, // [2,64,1152]
                                               float* __restrict__ out) {     // [M,1152]
    __shared__ _Float16 sA[BM * BK];
    __shared__ _Float16 sB[BN * BK];

    const int bid = blockIdx.x;
    const int mt = bid / NTILES;
    const int nt = bid - mt * NTILES;
    const int m0 = mt * BM;
    const int n0 = nt * BN;

    const int t = threadIdx.x;
    const int lane = t & 63;
    const int w = t >> 6;
    const int quad = lane >> 4;
    const int l15 = lane & 15;
    const int wm = (w >> 1) * 64;
    const int wn = (w & 1) * 64;

    // staging: chunk c = 16B = 8 halves; row = c>>2, col = (c&3)*8; 512 chunks/tile
    const int c0 = t, c1 = t + 256;
    const int ar0 = c0 >> 2, ac0 = (c0 & 3) * 8;
    const int ar1 = c1 >> 2, ac1 = (c1 & 3) * 8;

    const _Float16* gA = A + (size_t)m0 * IN_DIM;
    const _Float16* gB = Wh + (size_t)n0 * IN_DIM;

    f32x4 acc[4][4];
#pragma unroll
    for (int i = 0; i < 4; i++)
#pragma unroll
        for (int j = 0; j < 4; j++) acc[i][j] = (f32x4)0.f;

    for (int k0 = 0; k0 < IN_DIM; k0 += BK) {
        async16(gA + (size_t)ar0 * IN_DIM + k0 + ac0, &sA[c0 * 8]);
        async16(gA + (size_t)ar1 * IN_DIM + k0 + ac1, &sA[c1 * 8]);
        async16(gB + (size_t)ar0 * IN_DIM + k0 + ac0, &sB[c0 * 8]);
        async16(gB + (size_t)ar1 * IN_DIM + k0 + ac1, &sB[c1 * 8]);
        __syncthreads();  // compiler emits s_waitcnt vmcnt(0) before s_barrier

        f16x8 af[4], bf[4];
#pragma unroll
        for (int mi = 0; mi < 4; mi++)
            af[mi] = *(const f16x8*)&sA[(wm + mi * 16 + l15) * BK + quad * 8];
#pragma unroll
        for (int ni = 0; ni < 4; ni++)
            bf[ni] = *(const f16x8*)&sB[(wn + ni * 16 + l15) * BK + quad * 8];

#pragma unroll
        for (int mi = 0; mi < 4; mi++)
#pragma unroll
            for (int ni = 0; ni < 4; ni++)
                acc[mi][ni] = __builtin_amdgcn_mfma_f32_16x16x32_f16(af[mi], bf[ni],
                                                                     acc[mi][ni], 0, 0, 0);
        __syncthreads();
    }

    // epilogue: C/D layout col=lane&15, row=quad*4+reg (m89-verified)
    const float* t0 = table;
    const float* t1 = table + POS_SIZE * HIDDEN;
#pragma unroll
    for (int mi = 0; mi < 4; mi++) {
#pragma unroll
        for (int r = 0; r < 4; r++) {
            const int gm = m0 + wm + mi * 16 + quad * 4 + r;
            int px = pos[gm * 2];
            int py = pos[gm * 2 + 1];
            px = px < 0 ? 0 : px;
            py = py < 0 ? 0 : py;
            const int isPad = pad[gm];
            const float* rx = t0 + (size_t)px * HIDDEN;
            const float* ry = t1 + (size_t)py * HIDDEN;
            float* orow = out + (size_t)gm * HIDDEN;
#pragma unroll
            for (int ni = 0; ni < 4; ni++) {
                const int gn = n0 + wn + ni * 16 + l15;
                float pe = isPad ? 0.f : (rx[gn] + ry[gn]);
                orow[gn] = acc[mi][ni][r] + pe;
            }
        }
    }
}

// ---------------- fp32 fallback (only if ws too small) ----------------
__global__ __launch_bounds__(256) void fallback_naive(const float* __restrict__ A,
                                                      const float* __restrict__ W,
                                                      const int* __restrict__ pos,
                                                      const int* __restrict__ pad,
                                                      const float* __restrict__ table,
                                                      float* __restrict__ out) {
    long idx = (long)blockIdx.x * 256 + threadIdx.x;
    const long total = (long)M_TOTAL * HIDDEN;
    if (idx >= total) return;
    int m = (int)(idx / HIDDEN);
    int n = (int)(idx - (long)m * HIDDEN);
    const float* a = A + (size_t)m * IN_DIM;
    const float* wv = W + (size_t)n * IN_DIM;
    float s = 0.f;
    for (int k = 0; k < IN_DIM; k++) s += a[k] * wv[k];
    int px = pos[m * 2]; if (px < 0) px = 0;
    int py = pos[m * 2 + 1]; if (py < 0) py = 0;
    float pe = pad[m] ? 0.f : (table[(size_t)px * HIDDEN + n] +
                               table[(size_t)(POS_SIZE + py) * HIDDEN + n]);
    out[idx] = s + pe;
}

extern "C" void kernel_launch(void* const* d_in, const int* in_sizes, int n_in,
                              void* d_out, int out_size, void* d_ws, size_t ws_size,
                              hipStream_t stream) {
    const float* pixel = (const float*)d_in[0];
    const int* pos = (const int*)d_in[1];
    const int* pad = (const int*)d_in[2];
    const float* W = (const float*)d_in[3];
    const float* table = (const float*)d_in[4];
    float* out = (float*)d_out;

    const size_t nA = (size_t)M_TOTAL * IN_DIM;   // 50,331,648
    const size_t nW = (size_t)HIDDEN * IN_DIM;    // 884,736
    const size_t need = (nA + nW) * sizeof(_Float16);

    if (ws_size >= need) {
        _Float16* Ah = (_Float16*)d_ws;
        _Float16* Whh = Ah + nA;
        cvt_f32_f16<<<4096, 256, 0, stream>>>(pixel, Ah, (int)(nA / 8));
        cvt_f32_f16<<<432, 256, 0, stream>>>(W, Whh, (int)(nW / 8));
        gemm_pe<<<(M_TOTAL / BM) * NTILES, 256, 0, stream>>>(Ah, Whh, pos, pad, table, out);
    } else {
        long total = (long)M_TOTAL * HIDDEN;
        fallback_naive<<<(int)((total + 255) / 256), 256, 0, stream>>>(pixel, W, pos, pad,
                                                                       table, out);
    }
}